// Round 2
// baseline (1056.811 us; speedup 1.0000x reference)
//
#include <hip/hip_runtime.h>
#include <stdint.h>

#define BS 128
#define SL 512
#define HD 1024
#define DD 512
#define M_TOT (BS*SL)   // 65536

typedef __attribute__((ext_vector_type(8))) short short8;
typedef __attribute__((ext_vector_type(4))) float f32x4;

__device__ __forceinline__ unsigned short f32_bf16(float f) {
    union { float f; unsigned u; } v; v.f = f;
    unsigned u = v.u + 0x7FFFu + ((v.u >> 16) & 1u);
    return (unsigned short)(u >> 16);
}
__device__ __forceinline__ float bf16_f32(unsigned short h) {
    union { unsigned u; float f; } v; v.u = ((unsigned)h) << 16; return v.f;
}
__device__ __forceinline__ float fast_tanh(float x) {
    // tanh(x) = 1 - 2/(exp(2x)+1); saturates correctly at +/-inf
    float e = __expf(2.0f * x);
    return 1.0f - 2.0f / (e + 1.0f);
}
__device__ __forceinline__ void async_lds16(const void* g, void* l) {
    __builtin_amdgcn_global_load_lds(
        (const __attribute__((address_space(1))) unsigned int*)g,
        (__attribute__((address_space(3))) unsigned int*)l, 16, 0, 0);
}

// ---------------- pack Wq into bf16 hi/lo, MFMA-frag order (+ mask detect) --
// Tile (nb 0..3, ks 0..31): 16KB block = 4096 hi halves + 4096 lo halves.
// n = nb*128+cg*16+(l&15), k = ks*32+(l>>4)*8+j -> half index (cg*64+l)*8+j.
__global__ void pack_wq_kernel(const float* __restrict__ Wq,
                               unsigned short* __restrict__ P,
                               const unsigned* __restrict__ mw,
                               int* __restrict__ flag) {
    if (blockIdx.x == 0) {
        // mask dtype detect: any 32-bit word >1 in first 4KB => byte-packed bool
        unsigned bad = 0;
        for (int i = threadIdx.x; i < 1024; i += 256) bad |= (mw[i] > 1u) ? 1u : 0u;
        if (bad) atomicExch(flag, 1);
    }
    int t = blockIdx.x * 256 + threadIdx.x;   // 0..65535
    int d  = t >> 7;           // 0..511
    int h0 = (t & 127) << 3;   // 0..1016
    const float* src = Wq + (size_t)d * HD + h0;
    union { unsigned short s[8]; uint4 v; } a, b;
#pragma unroll
    for (int j = 0; j < 8; ++j) {
        float f = src[j];
        a.s[j] = f32_bf16(f);
        b.s[j] = f32_bf16(f - bf16_f32(a.s[j]));
    }
    int nb = d >> 7, cg = (d >> 4) & 7, lr = d & 15;
    int ks = h0 >> 5, q = (h0 >> 3) & 3;
    int l = q * 16 + lr;
    size_t base = (size_t)(nb * 32 + ks) * 8192 + (size_t)(cg * 64 + l) * 8;
    *(uint4*)(P + base)        = a.v;
    *(uint4*)(P + base + 4096) = b.v;
}

// ---------------- phase 1: score = vq . tanh(x @ Wq^T + bq) ----------------
// 128x128 tile, K=1024 in 32 steps. 4 waves (2x2), each 64x64 (4x4 of 16x16).
// 3-term bf16 split: xh*Wh + xl*Wh + xh*Wl. XCD-swizzled work mapping so the
// 4 nb-siblings of one row-tile land on one XCD (L2 fetches x once).
__launch_bounds__(256, 5)
__global__ void score_kernel(const float* __restrict__ x,
                             const unsigned short* __restrict__ packW,
                             const float* __restrict__ bq,
                             const float* __restrict__ vq,
                             float* __restrict__ score) {
    __shared__ unsigned short A_hi[4096];   // 8 KB, frag order, XOR-swizzled
    __shared__ unsigned short A_lo[4096];   // 8 KB
    __shared__ unsigned short Bt[8192];     // 16 KB: hi[0..4095], lo[4096..]

    const int bid = blockIdx.x;
    const int xcd = bid & 7;
    const int slot = bid >> 3;              // 0..255
    const int nb = slot & 3;                // N tile of 128
    const int m0 = (xcd + ((slot >> 2) << 3)) << 7;  // row tile * 128

    const int t = threadIdx.x;
    const int l = t & 63;
    const int w = t >> 6;
    const int wm = w & 1, wn = w >> 1;      // 2x2 wave grid

    f32x4 acc[4][4];
#pragma unroll
    for (int i = 0; i < 4; ++i)
#pragma unroll
        for (int j = 0; j < 4; ++j)
            acc[i][j] = (f32x4){0.f, 0.f, 0.f, 0.f};

    const char* Ahc = (const char*)A_hi;
    const char* Alc = (const char*)A_lo;

    for (int ks = 0; ks < 32; ++ks) {
        __syncthreads();
        // ---- stage B: async 16KB linear copy, LDS dest = base + lane*16 ----
        {
            const unsigned short* src = packW + (size_t)(nb * 32 + ks) * 8192;
            unsigned short* dst = Bt;
#pragma unroll
            for (int r = 0; r < 4; ++r)
                async_lds16(src + (size_t)(r * 256 + t) * 8, dst + (r * 256 + t) * 8);
        }
        // ---- stage A: 128 rows x 32 k fp32 -> bf16 hi/lo, XOR-swizzled ----
#pragma unroll
        for (int r = 0; r < 2; ++r) {
            int u = r * 256 + t;            // 0..511 (row, 8k) units
            int row = u >> 2, c8 = u & 3;
            const float4* xp = (const float4*)(x + (size_t)(m0 + row) * HD + ks * 32 + c8 * 8);
            float4 v0 = xp[0], v1 = xp[1];
            float ff[8] = {v0.x, v0.y, v0.z, v0.w, v1.x, v1.y, v1.z, v1.w};
            union { unsigned short s[8]; uint4 q4; } hi, lo;
#pragma unroll
            for (int j = 0; j < 8; ++j) {
                hi.s[j] = f32_bf16(ff[j]);
                lo.s[j] = f32_bf16(ff[j] - bf16_f32(hi.s[j]));
            }
            int rg = row >> 4, rr = row & 15;
            int off = (((rg * 64 + c8 * 16 + rr) * 16) ^ (c8 << 5));
            *(uint4*)((char*)A_hi + off) = hi.q4;
            *(uint4*)((char*)A_lo + off) = lo.q4;
        }
        __syncthreads();

        // ---- compute ----
        const short8* Bh = (const short8*)Bt;
        const short8* Bl = (const short8*)(Bt + 4096);
        short8 ah[4], al[4], bh[4], bl[4];
        const int xr = (l >> 4) << 5;
#pragma unroll
        for (int i = 0; i < 4; ++i) {
            int off = ((((wm * 4 + i) * 64 + l) * 16) ^ xr);
            ah[i] = *(const short8*)(Ahc + off);
            al[i] = *(const short8*)(Alc + off);
        }
#pragma unroll
        for (int j = 0; j < 4; ++j) {
            bh[j] = Bh[(wn * 4 + j) * 64 + l];
            bl[j] = Bl[(wn * 4 + j) * 64 + l];
        }
#pragma unroll
        for (int i = 0; i < 4; ++i)
#pragma unroll
            for (int j = 0; j < 4; ++j) {
                acc[i][j] = __builtin_amdgcn_mfma_f32_16x16x32_bf16(ah[i], bh[j], acc[i][j], 0, 0, 0);
                acc[i][j] = __builtin_amdgcn_mfma_f32_16x16x32_bf16(al[i], bh[j], acc[i][j], 0, 0, 0);
                acc[i][j] = __builtin_amdgcn_mfma_f32_16x16x32_bf16(ah[i], bl[j], acc[i][j], 0, 0, 0);
            }
    }

    // ---- epilogue: + bq, tanh, *vq, reduce over cols, atomicAdd ----
    // C/D layout: col = lane&15, row = (lane>>4)*4 + reg
    int q = l >> 4, c = l & 15;
#pragma unroll
    for (int i = 0; i < 4; ++i) {
        float rs[4] = {0.f, 0.f, 0.f, 0.f};
#pragma unroll
        for (int j = 0; j < 4; ++j) {
            int n = nb * 128 + wn * 64 + j * 16 + c;
            float bqv = bq[n], vqv = vq[n];
            f32x4 a4 = acc[i][j];
#pragma unroll
            for (int r = 0; r < 4; ++r)
                rs[r] += fast_tanh(a4[r] + bqv) * vqv;
        }
#pragma unroll
        for (int r = 0; r < 4; ++r) {
            float v = rs[r];
            v += __shfl_xor(v, 1);
            v += __shfl_xor(v, 2);
            v += __shfl_xor(v, 4);
            v += __shfl_xor(v, 8);
            if (c == 0)
                atomicAdd(&score[m0 + wm * 64 + i * 16 + q * 4 + r], v);
        }
    }
}

// ---------------- phase 2: masked softmax over sl=512 ----------------
__global__ void softmax_kernel(const float* __restrict__ score,
                               const void* __restrict__ maskp,
                               const int* __restrict__ flag,
                               float* __restrict__ wgt) {
    __shared__ float red[8];
    int b = blockIdx.x, t = threadIdx.x;
    int w = t >> 6, l = t & 63;
    bool u8 = (*flag != 0);
    int i0 = b * SL + t, i1 = i0 + 256;
    bool mk0, mk1;
    if (u8) {
        mk0 = ((const unsigned char*)maskp)[i0] != 0;
        mk1 = ((const unsigned char*)maskp)[i1] != 0;
    } else {
        mk0 = ((const int*)maskp)[i0] != 0;
        mk1 = ((const int*)maskp)[i1] != 0;
    }
    float s0 = mk0 ? -1000000.0f : score[i0];
    float s1 = mk1 ? -1000000.0f : score[i1];
    float mx = fmaxf(s0, s1);
    for (int d = 1; d < 64; d <<= 1) mx = fmaxf(mx, __shfl_xor(mx, d));
    if (l == 0) red[w] = mx;
    __syncthreads();
    mx = fmaxf(fmaxf(red[0], red[1]), fmaxf(red[2], red[3]));
    float e0 = expf(s0 - mx), e1 = expf(s1 - mx);
    float sm = e0 + e1;
    for (int d = 1; d < 64; d <<= 1) sm += __shfl_xor(sm, d);
    if (l == 0) red[4 + w] = sm;
    __syncthreads();
    sm = red[4] + red[5] + red[6] + red[7];
    float inv = 1.0f / sm;
    wgt[i0] = e0 * inv;
    wgt[i1] = e1 * inv;
}

// ---------------- phase 3a: partial[b][sc][h] = sum over 64 rows ----------
__global__ void wsum_partial_kernel(const float* __restrict__ x,
                                    const float* __restrict__ wgt,
                                    float* __restrict__ partial) {
    __shared__ float wsh[64];
    int b = blockIdx.x, sc = blockIdx.y, t = threadIdx.x;
    if (t < 64) wsh[t] = wgt[b * SL + sc * 64 + t];
    __syncthreads();
    const float4* xp = (const float4*)(x + ((size_t)b * SL + sc * 64) * HD) + t;
    float ax = 0.f, ay = 0.f, az = 0.f, aw = 0.f;
#pragma unroll 4
    for (int s = 0; s < 64; ++s) {
        float wv = wsh[s];
        float4 v = xp[(size_t)s * 256];
        ax += wv * v.x; ay += wv * v.y; az += wv * v.z; aw += wv * v.w;
    }
    float4 r = {ax, ay, az, aw};
    ((float4*)(partial + (size_t)(b * 8 + sc) * HD))[t] = r;
}

// ---------------- phase 3b: out[b][h] = sum_sc partial[b][sc][h] ----------
__global__ void wsum_reduce_kernel(const float* __restrict__ partial,
                                   float* __restrict__ out) {
    int i = blockIdx.x * 256 + threadIdx.x;   // float4 index, 0..32767
    int b = i >> 8, h4 = i & 255;
    const float4* p = (const float4*)partial + (size_t)b * 8 * 256 + h4;
    float4 a = p[0];
#pragma unroll
    for (int sc = 1; sc < 8; ++sc) {
        float4 v = p[sc * 256];
        a.x += v.x; a.y += v.y; a.z += v.z; a.w += v.w;
    }
    ((float4*)out)[i] = a;
}

extern "C" void kernel_launch(void* const* d_in, const int* in_sizes, int n_in,
                              void* d_out, int out_size, void* d_ws, size_t ws_size,
                              hipStream_t stream) {
    const float* x  = (const float*)d_in[0];
    const void* mask = d_in[1];
    const float* Wq = (const float*)d_in[2];
    const float* bq = (const float*)d_in[3];
    const float* vq = (const float*)d_in[4];
    float* out = (float*)d_out;

    char* ws = (char*)d_ws;
    unsigned short* packW = (unsigned short*)ws;                       // 2 MB
    float* score   = (float*)(ws + (2u << 20));                        // 256 KB
    int*   flag    = (int*)  (ws + (2u << 20) + (256u << 10));         // 4 B
    float* wgt     = (float*)(ws + (2u << 20) + (257u << 10));         // 256 KB
    float* partial = (float*)(ws + (3u << 20));                        // 4 MB

    // zero score + flag in one memset (they're adjacent)
    hipMemsetAsync(score, 0, (256u << 10) + 4, stream);

    pack_wq_kernel<<<256, 256, 0, stream>>>(Wq, packW, (const unsigned*)mask, flag);
    score_kernel<<<2048, 256, 0, stream>>>(x, packW, bq, vq, score);
    softmax_kernel<<<BS, 256, 0, stream>>>(score, mask, flag, wgt);
    wsum_partial_kernel<<<dim3(BS, 8), 256, 0, stream>>>(x, wgt, partial);
    wsum_reduce_kernel<<<128, 256, 0, stream>>>(partial, out);
}

// Round 3
// 526.069 us; speedup vs baseline: 2.0089x; 2.0089x over previous
//
#include <hip/hip_runtime.h>
#include <stdint.h>

#define BS 128
#define SL 512
#define HD 1024
#define DD 512
#define M_TOT (BS*SL)   // 65536

typedef __attribute__((ext_vector_type(8))) short short8;
typedef __attribute__((ext_vector_type(4))) float f32x4;

__device__ __forceinline__ unsigned short f32_bf16(float f) {
    union { float f; unsigned u; } v; v.f = f;
    unsigned u = v.u + 0x7FFFu + ((v.u >> 16) & 1u);
    return (unsigned short)(u >> 16);
}
__device__ __forceinline__ float bf16_f32(unsigned short h) {
    union { unsigned u; float f; } v; v.u = ((unsigned)h) << 16; return v.f;
}
__device__ __forceinline__ float fast_tanh(float x) {
    float e = __expf(2.0f * x);
    return 1.0f - 2.0f / (e + 1.0f);
}
__device__ __forceinline__ void async_lds16(const void* g, void* l) {
    __builtin_amdgcn_global_load_lds(
        (const __attribute__((address_space(1))) unsigned int*)g,
        (__attribute__((address_space(3))) unsigned int*)l, 16, 0, 0);
}

// ---------------- pack Wq into bf16 hi/lo, MFMA-frag order (+ mask detect) --
__global__ void pack_wq_kernel(const float* __restrict__ Wq,
                               unsigned short* __restrict__ P,
                               const unsigned* __restrict__ mw,
                               int* __restrict__ flag) {
    if (blockIdx.x == 0) {
        unsigned bad = 0;
        for (int i = threadIdx.x; i < 1024; i += 256) bad |= (mw[i] > 1u) ? 1u : 0u;
        if (bad) atomicExch(flag, 1);
    }
    int t = blockIdx.x * 256 + threadIdx.x;   // 0..65535
    int d  = t >> 7;           // 0..511
    int h0 = (t & 127) << 3;   // 0..1016
    const float* src = Wq + (size_t)d * HD + h0;
    union { unsigned short s[8]; uint4 v; } a, b;
#pragma unroll
    for (int j = 0; j < 8; ++j) {
        float f = src[j];
        a.s[j] = f32_bf16(f);
        b.s[j] = f32_bf16(f - bf16_f32(a.s[j]));
    }
    int nb = d >> 7, cg = (d >> 4) & 7, lr = d & 15;
    int ks = h0 >> 5, q = (h0 >> 3) & 3;
    int l = q * 16 + lr;
    size_t base = (size_t)(nb * 32 + ks) * 8192 + (size_t)(cg * 64 + l) * 8;
    *(uint4*)(P + base)        = a.v;
    *(uint4*)(P + base + 4096) = b.v;
}

// ---------------- phase 1: score = vq . tanh(x @ Wq^T + bq) ----------------
// 128x128 tile, K=1024 in 32 steps. 4 waves (2x2), each 64x64 (4x4 of 16x16).
// 3-term bf16 split. launch_bounds(256,3): budget ~170 regs/wave >= the ~152
// this kernel needs (64 acc + frags + 16 prefetch); (256,5) spilled 1.3 GB.
__launch_bounds__(256, 3)
__global__ void score_kernel(const float* __restrict__ x,
                             const unsigned short* __restrict__ packW,
                             const float* __restrict__ bq,
                             const float* __restrict__ vq,
                             float* __restrict__ score) {
    __shared__ unsigned short A_hi[4096];   // 8 KB, frag order, XOR-swizzled
    __shared__ unsigned short A_lo[4096];   // 8 KB
    __shared__ unsigned short Bt[8192];     // 16 KB: hi[0..4095], lo[4096..]

    const int bid = blockIdx.x;
    const int xcd = bid & 7;
    const int slot = bid >> 3;              // 0..255
    const int nb = slot & 3;                // N tile of 128
    const int m0 = (xcd + ((slot >> 2) << 3)) << 7;  // row tile * 128

    const int t = threadIdx.x;
    const int l = t & 63;
    const int w = t >> 6;
    const int wm = w & 1, wn = w >> 1;      // 2x2 wave grid

    f32x4 acc[4][4];
#pragma unroll
    for (int i = 0; i < 4; ++i)
#pragma unroll
        for (int j = 0; j < 4; ++j)
            acc[i][j] = (f32x4){0.f, 0.f, 0.f, 0.f};

    const char* Ahc = (const char*)A_hi;
    const char* Alc = (const char*)A_lo;

    // per-thread A-staging coordinates (2 units of (row, 8k) each)
    int arow[2], ac8[2];
#pragma unroll
    for (int r = 0; r < 2; ++r) {
        int u = r * 256 + t;
        arow[r] = u >> 2; ac8[r] = u & 3;
    }

    float4 px[2][2];
    // prefetch ks=0
#pragma unroll
    for (int r = 0; r < 2; ++r) {
        const float4* xp = (const float4*)(x + (size_t)(m0 + arow[r]) * HD + ac8[r] * 8);
        px[r][0] = xp[0]; px[r][1] = xp[1];
    }

    for (int ks = 0; ks < 32; ++ks) {
        __syncthreads();   // previous compute done -> LDS free
        // ---- stage B: async 16KB linear copy (frag-ordered in packW) ----
        {
            const unsigned short* src = packW + (size_t)(nb * 32 + ks) * 8192;
#pragma unroll
            for (int r = 0; r < 4; ++r)
                async_lds16(src + (size_t)(r * 256 + t) * 8, Bt + (r * 256 + t) * 8);
        }
        // ---- stage A: convert prefetched fp32 -> bf16 hi/lo, XOR-swizzled ----
#pragma unroll
        for (int r = 0; r < 2; ++r) {
            float4 v0 = px[r][0], v1 = px[r][1];
            float ff[8] = {v0.x, v0.y, v0.z, v0.w, v1.x, v1.y, v1.z, v1.w};
            union { unsigned short s[8]; uint4 q4; } hi, lo;
#pragma unroll
            for (int j = 0; j < 8; ++j) {
                hi.s[j] = f32_bf16(ff[j]);
                lo.s[j] = f32_bf16(ff[j] - bf16_f32(hi.s[j]));
            }
            int rg = arow[r] >> 4, rr = arow[r] & 15;
            int off = (((rg * 64 + ac8[r] * 16 + rr) * 16) ^ (ac8[r] << 5));
            *(uint4*)((char*)A_hi + off) = hi.q4;
            *(uint4*)((char*)A_lo + off) = lo.q4;
        }
        __syncthreads();   // drains A-writes + async B (+ any px loads in flight)

        // ---- prefetch x for ks+1: overlaps the MFMA block below ----
        if (ks < 31) {
#pragma unroll
            for (int r = 0; r < 2; ++r) {
                const float4* xp = (const float4*)(x + (size_t)(m0 + arow[r]) * HD
                                                   + (ks + 1) * 32 + ac8[r] * 8);
                px[r][0] = xp[0]; px[r][1] = xp[1];
            }
        }

        // ---- compute ----
        const short8* Bh = (const short8*)Bt;
        const short8* Bl = (const short8*)(Bt + 4096);
        short8 ah[4], al[4], bh[4], bl[4];
        const int xr = (l >> 4) << 5;
#pragma unroll
        for (int i = 0; i < 4; ++i) {
            int off = ((((wm * 4 + i) * 64 + l) * 16) ^ xr);
            ah[i] = *(const short8*)(Ahc + off);
            al[i] = *(const short8*)(Alc + off);
        }
#pragma unroll
        for (int j = 0; j < 4; ++j) {
            bh[j] = Bh[(wn * 4 + j) * 64 + l];
            bl[j] = Bl[(wn * 4 + j) * 64 + l];
        }
#pragma unroll
        for (int i = 0; i < 4; ++i)
#pragma unroll
            for (int j = 0; j < 4; ++j) {
                acc[i][j] = __builtin_amdgcn_mfma_f32_16x16x32_bf16(ah[i], bh[j], acc[i][j], 0, 0, 0);
                acc[i][j] = __builtin_amdgcn_mfma_f32_16x16x32_bf16(al[i], bh[j], acc[i][j], 0, 0, 0);
                acc[i][j] = __builtin_amdgcn_mfma_f32_16x16x32_bf16(ah[i], bl[j], acc[i][j], 0, 0, 0);
            }
    }

    // ---- epilogue: + bq, tanh, *vq, reduce over cols, atomicAdd ----
    // C/D layout: col = lane&15, row = (lane>>4)*4 + reg
    int q = l >> 4, c = l & 15;
#pragma unroll
    for (int i = 0; i < 4; ++i) {
        float rs[4] = {0.f, 0.f, 0.f, 0.f};
#pragma unroll
        for (int j = 0; j < 4; ++j) {
            int n = nb * 128 + wn * 64 + j * 16 + c;
            float bqv = bq[n], vqv = vq[n];
            f32x4 a4 = acc[i][j];
#pragma unroll
            for (int r = 0; r < 4; ++r)
                rs[r] += fast_tanh(a4[r] + bqv) * vqv;
        }
#pragma unroll
        for (int r = 0; r < 4; ++r) {
            float v = rs[r];
            v += __shfl_xor(v, 1);
            v += __shfl_xor(v, 2);
            v += __shfl_xor(v, 4);
            v += __shfl_xor(v, 8);
            if (c == 0)
                atomicAdd(&score[m0 + wm * 64 + i * 16 + q * 4 + r], v);
        }
    }
}

// ---------------- phase 2: masked softmax over sl=512 ----------------
__global__ void softmax_kernel(const float* __restrict__ score,
                               const void* __restrict__ maskp,
                               const int* __restrict__ flag,
                               float* __restrict__ wgt) {
    __shared__ float red[8];
    int b = blockIdx.x, t = threadIdx.x;
    int w = t >> 6, l = t & 63;
    bool u8 = (*flag != 0);
    int i0 = b * SL + t, i1 = i0 + 256;
    bool mk0, mk1;
    if (u8) {
        mk0 = ((const unsigned char*)maskp)[i0] != 0;
        mk1 = ((const unsigned char*)maskp)[i1] != 0;
    } else {
        mk0 = ((const int*)maskp)[i0] != 0;
        mk1 = ((const int*)maskp)[i1] != 0;
    }
    float s0 = mk0 ? -1000000.0f : score[i0];
    float s1 = mk1 ? -1000000.0f : score[i1];
    float mx = fmaxf(s0, s1);
    for (int d = 1; d < 64; d <<= 1) mx = fmaxf(mx, __shfl_xor(mx, d));
    if (l == 0) red[w] = mx;
    __syncthreads();
    mx = fmaxf(fmaxf(red[0], red[1]), fmaxf(red[2], red[3]));
    float e0 = expf(s0 - mx), e1 = expf(s1 - mx);
    float sm = e0 + e1;
    for (int d = 1; d < 64; d <<= 1) sm += __shfl_xor(sm, d);
    if (l == 0) red[4 + w] = sm;
    __syncthreads();
    sm = red[4] + red[5] + red[6] + red[7];
    float inv = 1.0f / sm;
    wgt[i0] = e0 * inv;
    wgt[i1] = e1 * inv;
}

// ---------------- phase 3a: partial[b][sc][h] = sum over 64 rows ----------
__global__ void wsum_partial_kernel(const float* __restrict__ x,
                                    const float* __restrict__ wgt,
                                    float* __restrict__ partial) {
    __shared__ float wsh[64];
    int b = blockIdx.x, sc = blockIdx.y, t = threadIdx.x;
    if (t < 64) wsh[t] = wgt[b * SL + sc * 64 + t];
    __syncthreads();
    const float4* xp = (const float4*)(x + ((size_t)b * SL + sc * 64) * HD) + t;
    float ax = 0.f, ay = 0.f, az = 0.f, aw = 0.f;
#pragma unroll 4
    for (int s = 0; s < 64; ++s) {
        float wv = wsh[s];
        float4 v = xp[(size_t)s * 256];
        ax += wv * v.x; ay += wv * v.y; az += wv * v.z; aw += wv * v.w;
    }
    float4 r = {ax, ay, az, aw};
    ((float4*)(partial + (size_t)(b * 8 + sc) * HD))[t] = r;
}

// ---------------- phase 3b: out[b][h] = sum_sc partial[b][sc][h] ----------
__global__ void wsum_reduce_kernel(const float* __restrict__ partial,
                                   float* __restrict__ out) {
    int i = blockIdx.x * 256 + threadIdx.x;   // float4 index, 0..32767
    int b = i >> 8, h4 = i & 255;
    const float4* p = (const float4*)partial + (size_t)b * 8 * 256 + h4;
    float4 a = p[0];
#pragma unroll
    for (int sc = 1; sc < 8; ++sc) {
        float4 v = p[sc * 256];
        a.x += v.x; a.y += v.y; a.z += v.z; a.w += v.w;
    }
    ((float4*)out)[i] = a;
}

extern "C" void kernel_launch(void* const* d_in, const int* in_sizes, int n_in,
                              void* d_out, int out_size, void* d_ws, size_t ws_size,
                              hipStream_t stream) {
    const float* x  = (const float*)d_in[0];
    const void* mask = d_in[1];
    const float* Wq = (const float*)d_in[2];
    const float* bq = (const float*)d_in[3];
    const float* vq = (const float*)d_in[4];
    float* out = (float*)d_out;

    char* ws = (char*)d_ws;
    unsigned short* packW = (unsigned short*)ws;                       // 2 MB
    float* score   = (float*)(ws + (2u << 20));                        // 256 KB
    int*   flag    = (int*)  (ws + (2u << 20) + (256u << 10));         // 4 B
    float* wgt     = (float*)(ws + (2u << 20) + (257u << 10));         // 256 KB
    float* partial = (float*)(ws + (3u << 20));                        // 4 MB

    hipMemsetAsync(score, 0, (256u << 10) + 4, stream);

    pack_wq_kernel<<<256, 256, 0, stream>>>(Wq, packW, (const unsigned*)mask, flag);
    score_kernel<<<2048, 256, 0, stream>>>(x, packW, bq, vq, score);
    softmax_kernel<<<BS, 256, 0, stream>>>(score, mask, flag, wgt);
    wsum_partial_kernel<<<dim3(BS, 8), 256, 0, stream>>>(x, wgt, partial);
    wsum_reduce_kernel<<<128, 256, 0, stream>>>(partial, out);
}